// Round 1
// baseline (179.854 us; speedup 1.0000x reference)
//
#include <hip/hip_runtime.h>

typedef unsigned short u16;
typedef __attribute__((ext_vector_type(8))) short short8;
typedef __attribute__((ext_vector_type(4))) float f32x4;

#define BB 4
#define LL 16
#define NTOK 64
#define DD 512
#define NH 8
#define HDIM 64
#define NSEQ 1024
#define E3 1536
#define INV_SCALE 0.04419417382415922f

__device__ __forceinline__ u16 f2bf(float f) {
  union { float f; unsigned u; } v; v.f = f;
  unsigned u = v.u;
  unsigned r = u + 0x7fffu + ((u >> 16) & 1u);
  return (u16)(r >> 16);
}
__device__ __forceinline__ float bf2f(u16 h) {
  union { unsigned u; float f; } v; v.u = ((unsigned)h) << 16;
  return v.f;
}

// ---------------- kernel 1: fp32 -> bf16 conversion of x and W_qkv ----------------
__global__ __launch_bounds__(256) void prep_convert(const float* __restrict__ x,
                                                    const float* __restrict__ w,
                                                    u16* __restrict__ xbf,
                                                    u16* __restrict__ wbf) {
  const int nx = (4096 * DD) / 4;   // 524288 float4s of x
  const int nw = (E3 * DD) / 4;     // 196608 float4s of W_qkv
  int i = blockIdx.x * 256 + threadIdx.x;
  if (i < nx) {
    float4 v = ((const float4*)x)[i];
    unsigned lo = (unsigned)f2bf(v.x) | ((unsigned)f2bf(v.y) << 16);
    unsigned hi = (unsigned)f2bf(v.z) | ((unsigned)f2bf(v.w) << 16);
    ((uint2*)xbf)[i] = make_uint2(lo, hi);
  } else if (i < nx + nw) {
    int j = i - nx;
    float4 v = ((const float4*)w)[j];
    unsigned lo = (unsigned)f2bf(v.x) | ((unsigned)f2bf(v.y) << 16);
    unsigned hi = (unsigned)f2bf(v.z) | ((unsigned)f2bf(v.w) << 16);
    ((uint2*)wbf)[j] = make_uint2(lo, hi);
  }
}

// ---------------- kernel 2: tqkv = time_embeddings @ W_tqkv^T  (fp32) ----------------
__global__ __launch_bounds__(192) void tproj(const float* __restrict__ te,
                                             const float* __restrict__ wt,
                                             float* __restrict__ tq) {
  __shared__ float row[DD];
  int bl = blockIdx.x;  // b*16 + l  (0..63)
  for (int i = threadIdx.x; i < DD; i += 192) row[i] = te[bl * DD + i];
  __syncthreads();
  int e = threadIdx.x;  // 0..191
  const float4* wr_ = (const float4*)&wt[e * DD];
  const float4* rr = (const float4*)row;
  float acc = 0.f;
#pragma unroll 4
  for (int k = 0; k < DD / 4; ++k) {
    float4 a = rr[k], b = wr_[k];
    acc += a.x * b.x + a.y * b.y + a.z * b.z + a.w * b.w;
  }
  tq[bl * 192 + e] = acc;
}

// ---------------- kernel 3: qkv GEMM + time add + scatter to [b,h,N,hd] bf16 ----------------
// C[m][e] = sum_k x[m][k] * W[e][k]   (m=4096, e=1536, k=512), B^T-form GEMM.
__global__ __launch_bounds__(256) void gemm_qkv(const u16* __restrict__ xb,
                                                const u16* __restrict__ wb,
                                                const float* __restrict__ tq,
                                                u16* __restrict__ qkv_out) {
  __shared__ u16 As[128][72];
  __shared__ u16 Bs[128][72];
  int bn = blockIdx.x;   // 0..11
  int bm = blockIdx.y;   // 0..31
  int tid = threadIdx.x;
  int w = tid >> 6, l = tid & 63;
  int wr = w >> 1, wc = w & 1;
  int l15 = l & 15, l16 = l >> 4;

  f32x4 acc[4][4] = {};

  for (int kt = 0; kt < DD; kt += 64) {
#pragma unroll
    for (int c = 0; c < 4; ++c) {
      int idx = c * 256 + tid;            // 0..1023 chunks of 8 bf16
      int row = idx >> 3, col = (idx & 7) * 8;
      uint4 va = *(const uint4*)&xb[(size_t)(bm * 128 + row) * DD + kt + col];
      *(uint4*)&As[row][col] = va;
      uint4 vb = *(const uint4*)&wb[(size_t)(bn * 128 + row) * DD + kt + col];
      *(uint4*)&Bs[row][col] = vb;
    }
    __syncthreads();
#pragma unroll
    for (int ks = 0; ks < 2; ++ks) {
      short8 af[4], bf[4];
#pragma unroll
      for (int mt = 0; mt < 4; ++mt)
        af[mt] = *(const short8*)&As[wr * 64 + mt * 16 + l15][ks * 32 + l16 * 8];
#pragma unroll
      for (int nt = 0; nt < 4; ++nt)
        bf[nt] = *(const short8*)&Bs[wc * 64 + nt * 16 + l15][ks * 32 + l16 * 8];
#pragma unroll
      for (int mt = 0; mt < 4; ++mt)
#pragma unroll
        for (int nt = 0; nt < 4; ++nt)
          acc[mt][nt] = __builtin_amdgcn_mfma_f32_16x16x32_bf16(af[mt], bf[nt], acc[mt][nt], 0, 0, 0);
    }
    __syncthreads();
  }

  // epilogue: add time-qkv, write q/k/v planes bf16 [part][b][h][N][hd]
#pragma unroll
  for (int mt = 0; mt < 4; ++mt) {
    int m0 = bm * 128 + wr * 64 + mt * 16 + l16 * 4;
#pragma unroll
    for (int nt = 0; nt < 4; ++nt) {
      int e = bn * 128 + wc * 64 + nt * 16 + l15;
      int part = e >> 9;
      int din = e & 511;
      int h = din >> 6, hd = din & 63;
#pragma unroll
      for (int r = 0; r < 4; ++r) {
        int m = m0 + r;
        int b = m >> 10, li = (m >> 6) & 15, tok = m & 63;
        float t = tq[(b * LL + li) * 192 + part * 64 + hd];
        float val = acc[mt][nt][r] + t;
        size_t oidx = (size_t)part * (BB * NH * NSEQ * HDIM) +
                      ((size_t)((b * NH + h) * NSEQ) + li * 64 + tok) * HDIM + hd;
        qkv_out[oidx] = f2bf(val);
      }
    }
  }
}

// ---------------- kernel 4: flash attention with per-frame bias, frame-causal ----------------
__global__ __launch_bounds__(256) void attn_kernel(const u16* __restrict__ qb,
                                                   const u16* __restrict__ kb,
                                                   const u16* __restrict__ vb,
                                                   const int* __restrict__ pos,
                                                   const float* __restrict__ emb,
                                                   float* __restrict__ out) {
  __shared__ u16 Qs[64][72];
  __shared__ u16 Ks[64][72];
  __shared__ u16 Vts[64][72];
  __shared__ u16 Ps[64][72];
  __shared__ float bias_s[64][16];

  int blk = blockIdx.x;            // b*128 + h*16 + qf
  int b = blk >> 7;
  int h = (blk >> 4) & 7;
  int qf = blk & 15;
  int tid = threadIdx.x;
  int w = tid >> 6;                // wave 0..3 owns q rows [16w,16w+16)
  int l = tid & 63;
  int l15 = l & 15, l16 = l >> 4;

  const u16* Qg = qb + ((size_t)((b * NH + h) * NSEQ) + qf * 64) * HDIM;
#pragma unroll
  for (int c = 0; c < 2; ++c) {
    int idx = c * 256 + tid;
    int row = idx >> 3, col = (idx & 7) * 8;
    *(uint4*)&Qs[row][col] = *(const uint4*)&Qg[row * HDIM + col];
  }
  __syncthreads();

  // bias_s[q][kf] = dot(Q[q,:], emb_table[clip(pos[b,qf,kf])+8])
#pragma unroll
  for (int j = 0; j < 4; ++j) {
    int idx = j * 256 + tid;       // 0..1023
    int q = idx >> 4, kf = idx & 15;
    int p = pos[(b * LL + qf) * LL + kf];
    p = (p < -8 ? -8 : (p > 8 ? 8 : p)) + 8;
    const float* ev = emb + p * HDIM;
    float acc = 0.f;
#pragma unroll 8
    for (int dd = 0; dd < HDIM; ++dd) acc += bf2f(Qs[q][dd]) * ev[dd];
    bias_s[q][kf] = acc;
  }
  __syncthreads();

  float m_r[4], l_r[4];
  f32x4 o[4] = {};
#pragma unroll
  for (int r = 0; r < 4; ++r) { m_r[r] = -1e30f; l_r[r] = 0.f; }

  for (int kf = 0; kf <= qf; ++kf) {
    const u16* Kg = kb + ((size_t)((b * NH + h) * NSEQ) + kf * 64) * HDIM;
    const u16* Vg = vb + ((size_t)((b * NH + h) * NSEQ) + kf * 64) * HDIM;
#pragma unroll
    for (int c = 0; c < 2; ++c) {
      int idx = c * 256 + tid;
      int row = idx >> 3, col = (idx & 7) * 8;
      *(uint4*)&Ks[row][col] = *(const uint4*)&Kg[row * HDIM + col];
      uint4 vv = *(const uint4*)&Vg[row * HDIM + col];
      const u16* pv = (const u16*)&vv;
#pragma unroll
      for (int jj = 0; jj < 8; ++jj) Vts[col + jj][row] = pv[jj];
    }
    __syncthreads();

    // S = Q K^T  (wave rows 16w..16w+15, keys 0..63 of this frame)
    f32x4 s[4] = {};
#pragma unroll
    for (int ks = 0; ks < 2; ++ks) {
      short8 a = *(const short8*)&Qs[w * 16 + l15][ks * 32 + l16 * 8];
#pragma unroll
      for (int nt = 0; nt < 4; ++nt) {
        short8 bq = *(const short8*)&Ks[nt * 16 + l15][ks * 32 + l16 * 8];
        s[nt] = __builtin_amdgcn_mfma_f32_16x16x32_bf16(a, bq, s[nt], 0, 0, 0);
      }
    }

    float vals[4][4], pmax[4], psum[4];
#pragma unroll
    for (int r = 0; r < 4; ++r) {
      float bsum = bias_s[w * 16 + l16 * 4 + r][kf];
      float mx = -1e30f;
#pragma unroll
      for (int nt = 0; nt < 4; ++nt) {
        float v = (s[nt][r] + bsum) * INV_SCALE;
        vals[nt][r] = v;
        mx = fmaxf(mx, v);
      }
      pmax[r] = mx;
    }
#pragma unroll
    for (int off = 1; off < 16; off <<= 1) {
#pragma unroll
      for (int r = 0; r < 4; ++r)
        pmax[r] = fmaxf(pmax[r], __shfl_xor(pmax[r], off));
    }
#pragma unroll
    for (int r = 0; r < 4; ++r) {
      float mn = fmaxf(m_r[r], pmax[r]);
      float sc = expf(m_r[r] - mn);
      m_r[r] = mn;
      float ps = 0.f;
#pragma unroll
      for (int nt = 0; nt < 4; ++nt) {
        float p = expf(vals[nt][r] - mn);
        vals[nt][r] = p;
        ps += p;
      }
      psum[r] = ps;
      l_r[r] *= sc;
#pragma unroll
      for (int dt = 0; dt < 4; ++dt) o[dt][r] *= sc;
    }
#pragma unroll
    for (int off = 1; off < 16; off <<= 1) {
#pragma unroll
      for (int r = 0; r < 4; ++r)
        psum[r] += __shfl_xor(psum[r], off);
    }
#pragma unroll
    for (int r = 0; r < 4; ++r) l_r[r] += psum[r];

    // P -> LDS (bf16), wave-private rows
#pragma unroll
    for (int nt = 0; nt < 4; ++nt)
#pragma unroll
      for (int r = 0; r < 4; ++r)
        Ps[w * 16 + l16 * 4 + r][nt * 16 + l15] = f2bf(vals[nt][r]);

    // O += P @ V
#pragma unroll
    for (int ks = 0; ks < 2; ++ks) {
      short8 a = *(const short8*)&Ps[w * 16 + l15][ks * 32 + l16 * 8];
#pragma unroll
      for (int dt = 0; dt < 4; ++dt) {
        short8 bv = *(const short8*)&Vts[dt * 16 + l15][ks * 32 + l16 * 8];
        o[dt] = __builtin_amdgcn_mfma_f32_16x16x32_bf16(a, bv, o[dt], 0, 0, 0);
      }
    }
    __syncthreads();
  }

  // normalize and write out fp32: out[b][qf][tok][h*64 + d]
#pragma unroll
  for (int r = 0; r < 4; ++r) l_r[r] = 1.f / l_r[r];
  float* outp = out + ((size_t)(b * LL + qf) * 64) * DD + h * 64;
#pragma unroll
  for (int dt = 0; dt < 4; ++dt) {
#pragma unroll
    for (int r = 0; r < 4; ++r) {
      int tok = w * 16 + l16 * 4 + r;
      outp[(size_t)tok * DD + dt * 16 + l15] = o[dt][r] * l_r[r];
    }
  }
}

// ---------------- launcher ----------------
extern "C" void kernel_launch(void* const* d_in, const int* in_sizes, int n_in,
                              void* d_out, int out_size, void* d_ws, size_t ws_size,
                              hipStream_t stream) {
  const float* x    = (const float*)d_in[0];
  const float* te   = (const float*)d_in[1];
  const int*   pos  = (const int*)d_in[2];
  // d_in[3] = mask: always tril over frames (frame-causal) -> handled structurally
  const float* wqkv = (const float*)d_in[4];
  const float* wt   = (const float*)d_in[5];
  const float* emb  = (const float*)d_in[6];
  float* out = (float*)d_out;
  char* ws = (char*)d_ws;

  // ws layout (bytes)
  const size_t OFF_XBF = 0;                                 // 4096*512*2   = 4,194,304
  const size_t OFF_WBF = OFF_XBF + (size_t)4096 * DD * 2;   // 1536*512*2   = 1,572,864
  const size_t OFF_TQ  = OFF_WBF + (size_t)E3 * DD * 2;     // 64*192*4     = 49,152
  const size_t OFF_QKV = OFF_TQ + (size_t)64 * 192 * 4;     // 3*4,194,304  = 12,582,912

  u16*   xbf = (u16*)(ws + OFF_XBF);
  u16*   wbf = (u16*)(ws + OFF_WBF);
  float* tq  = (float*)(ws + OFF_TQ);
  u16*   qkv = (u16*)(ws + OFF_QKV);
  const size_t PLANE = (size_t)BB * NH * NSEQ * HDIM;       // 2,097,152 elems

  prep_convert<<<2816, 256, 0, stream>>>(x, wqkv, xbf, wbf);
  tproj<<<64, 192, 0, stream>>>(te, wt, tq);
  gemm_qkv<<<dim3(12, 32), 256, 0, stream>>>(xbf, wbf, tq, qkv);
  attn_kernel<<<512, 256, 0, stream>>>(qkv, qkv + PLANE, qkv + 2 * PLANE, pos, emb, out);
}

// Round 2
// 162.232 us; speedup vs baseline: 1.1086x; 1.1086x over previous
//
#include <hip/hip_runtime.h>

typedef unsigned short u16;
typedef __attribute__((ext_vector_type(8))) short short8;
typedef __attribute__((ext_vector_type(4))) float f32x4;
typedef __attribute__((ext_vector_type(4))) u16 u16x4;

#define BB 4
#define LL 16
#define DD 512
#define NH 8
#define HDIM 64
#define NSEQ 1024
#define E3 1536
#define INV_SCALE 0.04419417382415922f

__device__ __forceinline__ u16 f2bf(float f) {
  union { float f; unsigned u; } v; v.f = f;
  unsigned u = v.u;
  unsigned r = u + 0x7fffu + ((u >> 16) & 1u);
  return (u16)(r >> 16);
}

// ---------------- kernel 1: fp32 -> bf16 conversion of x and W_qkv ----------------
__global__ __launch_bounds__(256) void prep_convert(const float* __restrict__ x,
                                                    const float* __restrict__ w,
                                                    u16* __restrict__ xbf,
                                                    u16* __restrict__ wbf) {
  const int nx = (4096 * DD) / 4;
  const int nw = (E3 * DD) / 4;
  int i = blockIdx.x * 256 + threadIdx.x;
  if (i < nx) {
    float4 v = ((const float4*)x)[i];
    unsigned lo = (unsigned)f2bf(v.x) | ((unsigned)f2bf(v.y) << 16);
    unsigned hi = (unsigned)f2bf(v.z) | ((unsigned)f2bf(v.w) << 16);
    ((uint2*)xbf)[i] = make_uint2(lo, hi);
  } else if (i < nx + nw) {
    int j = i - nx;
    float4 v = ((const float4*)w)[j];
    unsigned lo = (unsigned)f2bf(v.x) | ((unsigned)f2bf(v.y) << 16);
    unsigned hi = (unsigned)f2bf(v.z) | ((unsigned)f2bf(v.w) << 16);
    ((uint2*)wbf)[j] = make_uint2(lo, hi);
  }
}

// ---------------- kernel 2: tqkv = time_embeddings @ W_tqkv^T (fp32) ----------------
__global__ __launch_bounds__(192) void tproj(const float* __restrict__ te,
                                             const float* __restrict__ wt,
                                             float* __restrict__ tq) {
  __shared__ float row[DD];
  int bl = blockIdx.x;
  for (int i = threadIdx.x; i < DD; i += 192) row[i] = te[bl * DD + i];
  __syncthreads();
  int e = threadIdx.x;
  const float4* wr_ = (const float4*)&wt[e * DD];
  const float4* rr = (const float4*)row;
  float acc = 0.f;
#pragma unroll 4
  for (int k = 0; k < DD / 4; ++k) {
    float4 a = rr[k], b = wr_[k];
    acc += a.x * b.x + a.y * b.y + a.z * b.z + a.w * b.w;
  }
  tq[bl * 192 + e] = acc;
}

// ---------------- kernel 3: qkv GEMM (2-phase pipelined) + time add + scatter ----------------
// C[m][e] = sum_k x[m][k] * W[e][k]; m=4096, e=1536, k=512.
// Outputs: q,k planes [b][h][N][64] bf16; v plane TRANSPOSED [b][h][64][N] bf16.
__global__ __launch_bounds__(256) void gemm_qkv(const u16* __restrict__ xb,
                                                const u16* __restrict__ wb,
                                                const float* __restrict__ tq,
                                                u16* __restrict__ qp,
                                                u16* __restrict__ kp,
                                                u16* __restrict__ vt) {
  __shared__ u16 As[2][128][72];
  __shared__ u16 Bs[2][128][72];
  int bn = blockIdx.x;   // 0..11
  int bm = blockIdx.y;   // 0..31
  int tid = threadIdx.x;
  int w = tid >> 6, l = tid & 63;
  int wr = w >> 1, wc = w & 1;
  int l15 = l & 15, l16 = l >> 4;
  int r0 = tid >> 3, c0 = (tid & 7) * 8;   // staging: row base, col

  f32x4 acc[4][4] = {};
  uint4 ra[4], rb[4];

#define LOADT(kt)                                                                  \
  {                                                                                \
    _Pragma("unroll") for (int c = 0; c < 4; ++c) {                                \
      ra[c] = *(const uint4*)&xb[(size_t)(bm * 128 + c * 32 + r0) * DD + (kt) + c0]; \
      rb[c] = *(const uint4*)&wb[(size_t)(bn * 128 + c * 32 + r0) * DD + (kt) + c0]; \
    }                                                                              \
  }
#define STORET(buf)                                                                \
  {                                                                                \
    _Pragma("unroll") for (int c = 0; c < 4; ++c) {                                \
      *(uint4*)&As[buf][c * 32 + r0][c0] = ra[c];                                  \
      *(uint4*)&Bs[buf][c * 32 + r0][c0] = rb[c];                                  \
    }                                                                              \
  }

  LOADT(0);
  STORET(0);
  __syncthreads();
  int cur = 0;
#pragma unroll
  for (int i = 0; i < 8; ++i) {
    if (i < 7) LOADT((i + 1) * 64);
    // compute on buf cur
#pragma unroll
    for (int ks = 0; ks < 2; ++ks) {
      short8 af[4], bf[4];
#pragma unroll
      for (int mt = 0; mt < 4; ++mt)
        af[mt] = *(const short8*)&As[cur][wr * 64 + mt * 16 + l15][ks * 32 + l16 * 8];
#pragma unroll
      for (int nt = 0; nt < 4; ++nt)
        bf[nt] = *(const short8*)&Bs[cur][wc * 64 + nt * 16 + l15][ks * 32 + l16 * 8];
#pragma unroll
      for (int mt = 0; mt < 4; ++mt)
#pragma unroll
        for (int nt = 0; nt < 4; ++nt)
          acc[mt][nt] = __builtin_amdgcn_mfma_f32_16x16x32_bf16(af[mt], bf[nt], acc[mt][nt], 0, 0, 0);
    }
    if (i < 7) STORET(cur ^ 1);
    __syncthreads();
    cur ^= 1;
  }
#undef LOADT
#undef STORET

  // epilogue
  int part = bn >> 2;  // 0=q 1=k 2=v (uniform per block)
#pragma unroll
  for (int mt = 0; mt < 4; ++mt) {
    int m0 = bm * 128 + wr * 64 + mt * 16 + l16 * 4;
    int b = m0 >> 10;
    int li = (m0 >> 6) & 15;
    int nn0 = m0 & 1023;
    const float* tqrow = &tq[(b * LL + li) * 192 + part * 64];
#pragma unroll
    for (int nt = 0; nt < 4; ++nt) {
      int din = (bn & 3) * 128 + wc * 64 + nt * 16 + l15;
      int hh = din >> 6, hd = din & 63;
      float t = tqrow[hd];
      size_t bh = (size_t)(b * NH + hh);
      if (part == 2) {
        u16x4 pk;
#pragma unroll
        for (int r = 0; r < 4; ++r) pk[r] = f2bf(acc[mt][nt][r] + t);
        *(u16x4*)&vt[(bh * HDIM + hd) * NSEQ + nn0] = pk;
      } else {
        u16* dst = (part == 0) ? qp : kp;
#pragma unroll
        for (int r = 0; r < 4; ++r)
          dst[(bh * NSEQ + nn0 + r) * HDIM + hd] = f2bf(acc[mt][nt][r] + t);
      }
    }
  }
}

// ---------------- kernel 4: barrier-free flash attention ----------------
// grid: (b*8+h)*16 + (15-qf); 4 waves, wave rg owns q rows qf*64+rg*16 .. +16.
// Zero __syncthreads: K and V^T fragments come straight from global (L2),
// bias comes from an MFMA C-fragment, P does a wave-private LDS round trip.
__global__ __launch_bounds__(256) void attn_kernel(const u16* __restrict__ qp,
                                                   const u16* __restrict__ kp,
                                                   const u16* __restrict__ vt,
                                                   const int* __restrict__ pos,
                                                   const float* __restrict__ emb,
                                                   float* __restrict__ out) {
  __shared__ u16 Ps[4][16][72];
  int blk = blockIdx.x;
  int qf = 15 - (blk & 15);        // heavy blocks dispatch first
  int h = (blk >> 4) & 7;
  int b = blk >> 7;
  int tid = threadIdx.x;
  int rg = tid >> 6;
  int l = tid & 63;
  int l15 = l & 15, l16 = l >> 4;

  size_t bh = (size_t)(b * NH + h);

  // Q fragments for this wave's 16 rows, kept in registers for all frames
  const u16* Qg = qp + (bh * NSEQ + qf * 64 + rg * 16) * HDIM;
  short8 aq[2];
  aq[0] = *(const short8*)&Qg[l15 * HDIM + l16 * 8];
  aq[1] = *(const short8*)&Qg[l15 * HDIM + 32 + l16 * 8];

  // bias fragment: bias[q][kf] = Q . emb_table[clip(pos[b,qf,kf])]
  int pp = pos[(b * LL + qf) * LL + l15];
  pp = (pp < -8 ? -8 : (pp > 8 ? 8 : pp)) + 8;
  const float* ev = emb + pp * HDIM;
  f32x4 bfrag = {};
#pragma unroll
  for (int ks = 0; ks < 2; ++ks) {
    short8 ef;
#pragma unroll
    for (int j = 0; j < 8; ++j) ef[j] = (short)f2bf(ev[ks * 32 + l16 * 8 + j]);
    bfrag = __builtin_amdgcn_mfma_f32_16x16x32_bf16(aq[ks], ef, bfrag, 0, 0, 0);
  }

  float m_r[4], l_r[4];
  f32x4 o[4] = {};
#pragma unroll
  for (int r = 0; r < 4; ++r) { m_r[r] = -1e30f; l_r[r] = 0.f; }

  const u16* Kb = kp + bh * NSEQ * HDIM;
  const u16* Vb = vt + bh * HDIM * NSEQ;

  for (int kf = 0; kf <= qf; ++kf) {
    // K fragments straight from global (L2-resident)
    const u16* Kf = Kb + kf * 64 * HDIM;
    short8 kfr[4][2];
#pragma unroll
    for (int nt = 0; nt < 4; ++nt)
#pragma unroll
      for (int ks = 0; ks < 2; ++ks)
        kfr[nt][ks] = *(const short8*)&Kf[(nt * 16 + l15) * HDIM + ks * 32 + l16 * 8];

    f32x4 s[4] = {};
#pragma unroll
    for (int ks = 0; ks < 2; ++ks)
#pragma unroll
      for (int nt = 0; nt < 4; ++nt)
        s[nt] = __builtin_amdgcn_mfma_f32_16x16x32_bf16(aq[ks], kfr[nt][ks], s[nt], 0, 0, 0);

    // broadcast bias[row][kf] from the C-fragment lane holding column kf
    float bb[4];
    int srcl = (l & 48) + kf;
#pragma unroll
    for (int r = 0; r < 4; ++r) bb[r] = __shfl(bfrag[r], srcl);

    float vals[4][4], pmax[4], psum[4];
#pragma unroll
    for (int r = 0; r < 4; ++r) pmax[r] = -1e30f;
#pragma unroll
    for (int nt = 0; nt < 4; ++nt)
#pragma unroll
      for (int r = 0; r < 4; ++r) {
        float v = (s[nt][r] + bb[r]) * INV_SCALE;
        vals[nt][r] = v;
        pmax[r] = fmaxf(pmax[r], v);
      }
#pragma unroll
    for (int off = 1; off < 16; off <<= 1)
#pragma unroll
      for (int r = 0; r < 4; ++r) pmax[r] = fmaxf(pmax[r], __shfl_xor(pmax[r], off));

#pragma unroll
    for (int r = 0; r < 4; ++r) {
      float mn = fmaxf(m_r[r], pmax[r]);
      float sc = __expf(m_r[r] - mn);
      m_r[r] = mn;
      float ps = 0.f;
#pragma unroll
      for (int nt = 0; nt < 4; ++nt) {
        float pv = __expf(vals[nt][r] - mn);
        vals[nt][r] = pv;
        ps += pv;
      }
      psum[r] = ps;
      l_r[r] *= sc;
#pragma unroll
      for (int dt = 0; dt < 4; ++dt) o[dt][r] *= sc;
    }
#pragma unroll
    for (int off = 1; off < 16; off <<= 1)
#pragma unroll
      for (int r = 0; r < 4; ++r) psum[r] += __shfl_xor(psum[r], off);
#pragma unroll
    for (int r = 0; r < 4; ++r) l_r[r] += psum[r];

    // P: C-layout -> A-layout via wave-private LDS (no barrier needed)
#pragma unroll
    for (int nt = 0; nt < 4; ++nt)
#pragma unroll
      for (int r = 0; r < 4; ++r)
        Ps[rg][l16 * 4 + r][nt * 16 + l15] = f2bf(vals[nt][r]);
    short8 pa[2];
    pa[0] = *(const short8*)&Ps[rg][l15][l16 * 8];
    pa[1] = *(const short8*)&Ps[rg][l15][32 + l16 * 8];

    // V^T fragments straight from global
    short8 vfr[4][2];
#pragma unroll
    for (int dt = 0; dt < 4; ++dt)
#pragma unroll
      for (int ks = 0; ks < 2; ++ks)
        vfr[dt][ks] = *(const short8*)&Vb[(dt * 16 + l15) * NSEQ + kf * 64 + ks * 32 + l16 * 8];
#pragma unroll
    for (int ks = 0; ks < 2; ++ks)
#pragma unroll
      for (int dt = 0; dt < 4; ++dt)
        o[dt] = __builtin_amdgcn_mfma_f32_16x16x32_bf16(pa[ks], vfr[dt][ks], o[dt], 0, 0, 0);
  }

  float* outp = out + ((size_t)(b * LL + qf) * 64 + rg * 16) * DD + h * 64;
#pragma unroll
  for (int r = 0; r < 4; ++r) {
    float inv = 1.0f / l_r[r];
#pragma unroll
    for (int dt = 0; dt < 4; ++dt)
      outp[(size_t)(l16 * 4 + r) * DD + dt * 16 + l15] = o[dt][r] * inv;
  }
}

// ---------------- launcher ----------------
extern "C" void kernel_launch(void* const* d_in, const int* in_sizes, int n_in,
                              void* d_out, int out_size, void* d_ws, size_t ws_size,
                              hipStream_t stream) {
  const float* x    = (const float*)d_in[0];
  const float* te   = (const float*)d_in[1];
  const int*   pos  = (const int*)d_in[2];
  // d_in[3] = mask: structurally frame-causal (tril)
  const float* wqkv = (const float*)d_in[4];
  const float* wt   = (const float*)d_in[5];
  const float* emb  = (const float*)d_in[6];
  float* out = (float*)d_out;
  char* ws = (char*)d_ws;

  const size_t OFF_XBF = 0;
  const size_t OFF_WBF = OFF_XBF + (size_t)4096 * DD * 2;
  const size_t OFF_TQ  = OFF_WBF + (size_t)E3 * DD * 2;
  const size_t OFF_QKV = OFF_TQ + (size_t)64 * 192 * 4;
  const size_t PLANE = (size_t)BB * NH * NSEQ * HDIM;  // elems per plane

  u16*   xbf = (u16*)(ws + OFF_XBF);
  u16*   wbf = (u16*)(ws + OFF_WBF);
  float* tq  = (float*)(ws + OFF_TQ);
  u16*   qpl = (u16*)(ws + OFF_QKV);
  u16*   kpl = qpl + PLANE;
  u16*   vtl = qpl + 2 * PLANE;

  prep_convert<<<2816, 256, 0, stream>>>(x, wqkv, xbf, wbf);
  tproj<<<64, 192, 0, stream>>>(te, wt, tq);
  gemm_qkv<<<dim3(12, 32), 256, 0, stream>>>(xbf, wbf, tq, qpl, kpl, vtl);
  attn_kernel<<<512, 256, 0, stream>>>(qpl, kpl, vtl, pos, emb, out);
}